// Round 1
// 6805.463 us; speedup vs baseline: 1.3615x; 1.3615x over previous
//
#include <hip/hip_runtime.h>

typedef unsigned short u16;
typedef __attribute__((ext_vector_type(8))) short bfrag;   // 8 bf16 (4 VGPRs)
typedef __attribute__((ext_vector_type(4))) float f32x4;

__device__ __forceinline__ float b2f(u16 u){
  unsigned x = ((unsigned)u) << 16;
  return __uint_as_float(x);
}
__device__ __forceinline__ u16 f2b_rn(float f){
  unsigned x = __float_as_uint(f);
  unsigned r = x + 0x7FFFu + ((x >> 16) & 1u);
  return (u16)(r >> 16);
}

__device__ __forceinline__ float wred_sum(float v){
  #pragma unroll
  for (int o = 32; o > 0; o >>= 1) v += __shfl_down(v, o, 64);
  return v;
}
__device__ __forceinline__ float wred_max(float v){
  #pragma unroll
  for (int o = 32; o > 0; o >>= 1) v = fmaxf(v, __shfl_down(v, o, 64));
  return v;
}

// runtime-dtype loads: bf=1 -> buffer is bf16 (u16), bf=0 -> f32. Element index i.
__device__ __forceinline__ float ldv1(const void* p, size_t i, int bf){
  return bf ? b2f(((const u16*)p)[i]) : ((const float*)p)[i];
}

__device__ __forceinline__ void gl_lds16(const u16* g, u16* l){
  __builtin_amdgcn_global_load_lds(
      (const __attribute__((address_space(1))) void*)g,
      (__attribute__((address_space(3))) void*)l, 16, 0, 0);
}

__global__ void zero2(float* p){ if (threadIdx.x < 2) p[threadIdx.x] = 0.0f; }

// bf16 N(0,1): |x| <= ~6. f32 read as u16s: even u16s are random mantissa
// bits -> ~47% decode to |x|>100 or NaN.
__global__ void detect_dtype(const u16* __restrict__ enc, float* __restrict__ flagp){
  if (threadIdx.x == 0){
    int cnt = 0;
    for (int i = 0; i < 512; ++i){
      float v = b2f(enc[i]);
      if (!(fabsf(v) <= 100.0f)) ++cnt;
    }
    flagp[2] = (cnt > 16) ? 0.0f : 1.0f;
  }
}

__global__ __launch_bounds__(256) void upcast_flag(const void* __restrict__ in,
                                                   float4* __restrict__ out, int n4,
                                                   const float* __restrict__ flagp){
  int bf = (flagp[2] != 0.0f);
  int i = blockIdx.x * 256 + threadIdx.x;
  if (i < n4){
    if (bf){
      ushort4 u = ((const ushort4*)in)[i];
      out[i] = make_float4(b2f(u.x), b2f(u.y), b2f(u.z), b2f(u.w));
    } else {
      out[i] = ((const float4*)in)[i];
    }
  }
}

// Split source into bf16 hi/lo planes, 8 elems per thread.
// useflag=1: source dtype per flagp[2] (bf16 -> hi=value, lo=0). useflag=0: f32.
__global__ __launch_bounds__(256) void split8(
    const void* __restrict__ in, size_t eoff,
    u16* __restrict__ hi, u16* __restrict__ lo,
    int n8, int useflag, const float* __restrict__ flagp)
{
  int i = blockIdx.x * 256 + threadIdx.x;
  if (i >= n8) return;
  int bf = useflag ? (flagp[2] != 0.0f) : 0;
  union { bfrag v; u16 us[8]; } H, L;
  if (bf){
    const u16* p = (const u16*)in + eoff;
    H.v = *(const bfrag*)(p + (size_t)i * 8);
    #pragma unroll
    for (int e = 0; e < 8; ++e) L.us[e] = 0;
  } else {
    const float* p = (const float*)in + eoff;
    float4 a = *(const float4*)(p + (size_t)i * 8);
    float4 b = *(const float4*)(p + (size_t)i * 8 + 4);
    float xs[8] = {a.x, a.y, a.z, a.w, b.x, b.y, b.z, b.w};
    #pragma unroll
    for (int e = 0; e < 8; ++e){
      u16 h = f2b_rn(xs[e]);
      H.us[e] = h;
      L.us[e] = f2b_rn(xs[e] - b2f(h));
    }
  }
  *(bfrag*)(hi + (size_t)i * 8) = H.v;
  *(bfrag*)(lo + (size_t)i * 8) = L.v;
}

// Pure-bf16 hi/lo 3-MFMA NT-GEMM: C[M,N] = (Xh+Xl)[M,K] @ (Wh+Wl)[N,K]^T + bias.
// Tile BM x 128, BK=32, 4 waves, global_load_lds staging into linear LDS
// (conflict-free ds_read_b128). BM=128: waves 2x2 of 64x64. BM=64: waves 1x4
// of 64x32. osplit=1: write hi/lo bf16 planes (post-relu) instead of f32.
template<int BM>
__global__ __launch_bounds__(256) void gemm_bf3(
    const u16* __restrict__ Xh, const u16* __restrict__ Xl,
    const u16* __restrict__ Wh, const u16* __restrict__ Wl,
    const void* __restrict__ bias, size_t bOff,
    float* __restrict__ Cf, u16* __restrict__ Ch, u16* __restrict__ Cl,
    int K, int ldc, int relu, int osplit, const float* __restrict__ flagp)
{
  constexpr int SEGA = BM / 16;            // 1KB segments per X plane
  constexpr int TS   = 2 * SEGA + 16;      // total segments (4 planes)
  constexpr int PW   = TS / 4;             // segments staged per wave
  constexpr int NI   = (BM == 128) ? 4 : 2;
  __shared__ u16 lds[TS * 512];

  const int tid  = threadIdx.x;
  const int w    = tid >> 6;
  const int lane = tid & 63;
  const int q    = lane >> 4;
  const int t16  = lane & 15;
  const int bm0  = blockIdx.y * BM;
  const int bn0  = blockIdx.x * 128;
  const int wm   = (BM == 128) ? (w & 1) * 64 : 0;
  const int wn   = (BM == 128) ? (w >> 1) * 64 : w * 32;
  const int lr   = lane >> 2;              // 0..15: row within segment
  const int lc   = (lane & 3) * 8;         // elem col within 32-wide k-tile

  // per-wave staging descriptors (fixed across K)
  const u16* srcb[PW];
  u16* dstb[PW];
  #pragma unroll
  for (int j = 0; j < PW; ++j){
    int chunk = w * PW + j;
    const u16* plane; int seg, rbase;
    if (chunk < SEGA)            { plane = Xh; seg = chunk;              rbase = bm0; }
    else if (chunk < 2*SEGA)     { plane = Xl; seg = chunk - SEGA;       rbase = bm0; }
    else if (chunk < 2*SEGA + 8) { plane = Wh; seg = chunk - 2*SEGA;     rbase = bn0; }
    else                         { plane = Wl; seg = chunk - 2*SEGA - 8; rbase = bn0; }
    srcb[j] = plane + (size_t)(rbase + seg * 16 + lr) * K + lc;
    dstb[j] = &lds[chunk * 512];
  }

  const u16* lAh = lds;
  const u16* lAl = lds + SEGA * 512;
  const u16* lWh = lds + 2 * SEGA * 512;
  const u16* lWl = lds + 2 * SEGA * 512 + 8 * 512;

  f32x4 acc[4][NI];
  #pragma unroll
  for (int mi = 0; mi < 4; ++mi)
    #pragma unroll
    for (int ni = 0; ni < NI; ++ni)
      acc[mi][ni] = (f32x4){0.f, 0.f, 0.f, 0.f};

  for (int k0 = 0; k0 < K; k0 += 32){
    #pragma unroll
    for (int j = 0; j < PW; ++j)
      gl_lds16(srcb[j] + k0, dstb[j]);
    __syncthreads();                      // vmcnt drained -> LDS tile ready

    bfrag ah[4], al[4], bh[NI], bl[NI];
    #pragma unroll
    for (int mi = 0; mi < 4; ++mi){
      ah[mi] = *(const bfrag*)&lAh[(wm + mi * 16 + t16) * 32 + q * 8];
      al[mi] = *(const bfrag*)&lAl[(wm + mi * 16 + t16) * 32 + q * 8];
    }
    #pragma unroll
    for (int ni = 0; ni < NI; ++ni){
      bh[ni] = *(const bfrag*)&lWh[(wn + ni * 16 + t16) * 32 + q * 8];
      bl[ni] = *(const bfrag*)&lWl[(wn + ni * 16 + t16) * 32 + q * 8];
    }
    #pragma unroll
    for (int mi = 0; mi < 4; ++mi)
      #pragma unroll
      for (int ni = 0; ni < NI; ++ni){
        acc[mi][ni] = __builtin_amdgcn_mfma_f32_16x16x32_bf16(ah[mi], bh[ni], acc[mi][ni], 0, 0, 0);
        acc[mi][ni] = __builtin_amdgcn_mfma_f32_16x16x32_bf16(al[mi], bh[ni], acc[mi][ni], 0, 0, 0);
        acc[mi][ni] = __builtin_amdgcn_mfma_f32_16x16x32_bf16(ah[mi], bl[ni], acc[mi][ni], 0, 0, 0);
      }
    __syncthreads();                      // all reads done before next stage
  }

  const int bf = (flagp[2] != 0.0f);
  float bv[NI];
  #pragma unroll
  for (int ni = 0; ni < NI; ++ni)
    bv[ni] = ldv1(bias, bOff + bn0 + wn + ni * 16 + t16, bf);
  #pragma unroll
  for (int mi = 0; mi < 4; ++mi){
    #pragma unroll
    for (int r = 0; r < 4; ++r){
      int row = bm0 + wm + mi * 16 + q * 4 + r;
      size_t rb = (size_t)row * ldc;
      #pragma unroll
      for (int ni = 0; ni < NI; ++ni){
        float v = acc[mi][ni][r] + bv[ni];
        if (relu) v = fmaxf(v, 0.0f);
        int col = bn0 + wn + ni * 16 + t16;
        if (osplit){
          u16 h = f2b_rn(v);
          Ch[rb + col] = h;
          Cl[rb + col] = f2b_rn(v - b2f(h));
        } else {
          Cf[rb + col] = v;
        }
      }
    }
  }
}

// scores[bh,q,k] = 0.125 * Q[b,q,h,:] . K[b,k,h,:]; batched 128 over z, f32.
__global__ __launch_bounds__(256) void gemm_qk(
    const float* __restrict__ Q, const float* __restrict__ Km, float* __restrict__ S)
{
  int bh = blockIdx.z;
  int b = bh >> 4, h = bh & 15;
  size_t offQ = (size_t)b * 512 * 1024 + (size_t)h * 64;
  size_t offC = (size_t)bh * 512 * 512;
  __shared__ float As[8][132];
  __shared__ float Bs[8][132];
  int tid = threadIdx.x;
  int tx = tid & 15, ty = tid >> 4;
  int bm0 = blockIdx.y * 128, bn0 = blockIdx.x * 128;
  int arow = tid >> 1;
  int acol = (tid & 1) * 4;
  float acc[8][8] = {};
  for (int k0 = 0; k0 < 64; k0 += 8){
    float4 xa = *(const float4*)(Q  + offQ + (size_t)(bm0 + arow) * 1024 + k0 + acol);
    float4 wa = *(const float4*)(Km + offQ + (size_t)(bn0 + arow) * 1024 + k0 + acol);
    __syncthreads();
    As[acol+0][arow]=xa.x; As[acol+1][arow]=xa.y; As[acol+2][arow]=xa.z; As[acol+3][arow]=xa.w;
    Bs[acol+0][arow]=wa.x; Bs[acol+1][arow]=wa.y; Bs[acol+2][arow]=wa.z; Bs[acol+3][arow]=wa.w;
    __syncthreads();
    #pragma unroll
    for (int kk = 0; kk < 8; ++kk){
      float a[8], b2[8];
      *(float4*)&a[0]  = *(const float4*)&As[kk][ty*8];
      *(float4*)&a[4]  = *(const float4*)&As[kk][ty*8+4];
      *(float4*)&b2[0] = *(const float4*)&Bs[kk][tx*8];
      *(float4*)&b2[4] = *(const float4*)&Bs[kk][tx*8+4];
      #pragma unroll
      for (int i = 0; i < 8; ++i)
        #pragma unroll
        for (int j = 0; j < 8; ++j)
          acc[i][j] = fmaf(a[i], b2[j], acc[i][j]);
    }
  }
  #pragma unroll
  for (int i = 0; i < 8; ++i)
    #pragma unroll
    for (int j = 0; j < 8; ++j)
      S[offC + (size_t)(bm0 + ty*8 + i) * 512 + (bn0 + tx*8 + j)] = acc[i][j] * 0.125f;
}

__global__ __launch_bounds__(256) void softmax512(float* __restrict__ S){
  size_t base = (size_t)blockIdx.x * 512;
  int tid = threadIdx.x;
  float a = S[base + tid], b = S[base + tid + 256];
  __shared__ float red[4];
  float m = wred_max(fmaxf(a, b));
  if ((tid & 63) == 0) red[tid >> 6] = m;
  __syncthreads();
  float bm = fmaxf(fmaxf(red[0], red[1]), fmaxf(red[2], red[3]));
  __syncthreads();
  float e0 = expf(a - bm), e1 = expf(b - bm);
  float s = wred_sum(e0 + e1);
  if ((tid & 63) == 0) red[tid >> 6] = s;
  __syncthreads();
  float inv = 1.0f / (red[0] + red[1] + red[2] + red[3]);
  S[base + tid] = e0 * inv;
  S[base + tid + 256] = e1 * inv;
}

// ctx[b,q,h,:] = sum_k P[bh,q,k] * V[b,k,h,:]
__global__ __launch_bounds__(256) void attn_ctx(
    const float* __restrict__ P, const float* __restrict__ V, float* __restrict__ O)
{
  int bh = blockIdx.z;
  int b = bh >> 4, h = bh & 15;
  const float* Pp = P + (size_t)bh * 512 * 512;
  const float* Vp = V + (size_t)b * 512 * 1024 + h * 64;
  float*       Op = O + (size_t)b * 512 * 1024 + h * 64;
  int q0 = blockIdx.y * 64;
  __shared__ float As[16][68];
  __shared__ float Bs[16][68];
  int tid = threadIdx.x;
  int tx = tid & 15, ty = tid >> 4;
  int arow = tid >> 2;
  int acol = (tid & 3) * 4;
  int vrow = tid >> 4;
  int vcol = (tid & 15) * 4;
  float acc[4][4] = {};
  for (int k0 = 0; k0 < 512; k0 += 16){
    float4 pv = *(const float4*)(Pp + (size_t)(q0 + arow) * 512 + k0 + acol);
    float4 vv = *(const float4*)(Vp + (size_t)(k0 + vrow) * 1024 + vcol);
    __syncthreads();
    As[acol+0][arow] = pv.x; As[acol+1][arow] = pv.y;
    As[acol+2][arow] = pv.z; As[acol+3][arow] = pv.w;
    *(float4*)&Bs[vrow][vcol] = vv;
    __syncthreads();
    #pragma unroll
    for (int kk = 0; kk < 16; ++kk){
      float a[4], b[4];
      *(float4*)a = *(const float4*)&As[kk][ty*4];
      *(float4*)b = *(const float4*)&Bs[kk][tx*4];
      #pragma unroll
      for (int i = 0; i < 4; ++i)
        #pragma unroll
        for (int j = 0; j < 4; ++j)
          acc[i][j] = fmaf(a[i], b[j], acc[i][j]);
    }
  }
  #pragma unroll
  for (int i = 0; i < 4; ++i)
    #pragma unroll
    for (int j = 0; j < 4; ++j)
      Op[(size_t)(q0 + ty*4 + i) * 1024 + tx*4 + j] = acc[i][j];
}

// out = LN(x1+x2)*g + b ; g,b element-offset eo, dtype per flag
__global__ __launch_bounds__(256) void ln_off(
    const float* __restrict__ x1, const float* __restrict__ x2,
    const void* __restrict__ g, const void* __restrict__ b, size_t eo,
    float* __restrict__ out, const float* __restrict__ flagp)
{
  int bf = (flagp[2] != 0.0f);
  int row = blockIdx.x, tid = threadIdx.x;
  size_t base = (size_t)row * 1024;
  float v[4]; float s = 0.0f;
  #pragma unroll
  for (int j = 0; j < 4; ++j){
    int c = tid + j * 256;
    v[j] = x1[base + c] + x2[base + c];
    s += v[j];
  }
  __shared__ float red[4];
  s = wred_sum(s);
  if ((tid & 63) == 0) red[tid >> 6] = s;
  __syncthreads();
  float mean = (red[0] + red[1] + red[2] + red[3]) * (1.0f / 1024.0f);
  __syncthreads();
  float sq = 0.0f;
  #pragma unroll
  for (int j = 0; j < 4; ++j){ float d = v[j] - mean; sq += d * d; }
  sq = wred_sum(sq);
  if ((tid & 63) == 0) red[tid >> 6] = sq;
  __syncthreads();
  float inv = rsqrtf((red[0] + red[1] + red[2] + red[3]) * (1.0f / 1024.0f) + 1e-5f);
  #pragma unroll
  for (int j = 0; j < 4; ++j){
    int c = tid + j * 256;
    out[base + c] = (v[j] - mean) * inv * ldv1(g, eo + c, bf) + ldv1(b, eo + c, bf);
  }
}

__global__ __launch_bounds__(256) void loss_row(
    const float* __restrict__ A, const void* __restrict__ cls_w, const void* __restrict__ cls_b,
    const int* __restrict__ labels, const int* __restrict__ maskA, const int* __restrict__ cand,
    float* __restrict__ acc, float* __restrict__ out, const float* __restrict__ flagp)
{
  int bf = (flagp[2] != 0.0f);
  int r = blockIdx.x, tid = threadIdx.x;
  const float* a = A + (size_t)r * 1024;
  float s0 = 0.0f, s1 = 0.0f;
  #pragma unroll
  for (int j = 0; j < 4; ++j){
    int c = tid + j * 256;
    float x = a[c];
    s0 += x * ldv1(cls_w, c, bf);
    s1 += x * ldv1(cls_w, 1024 + c, bf);
  }
  __shared__ float red0[4], red1[4];
  s0 = wred_sum(s0); s1 = wred_sum(s1);
  if ((tid & 63) == 0){ red0[tid >> 6] = s0; red1[tid >> 6] = s1; }
  __syncthreads();
  if (tid == 0){
    float e0 = red0[0] + red0[1] + red0[2] + red0[3] + ldv1(cls_b, 0, bf);
    float e1 = red1[0] + red1[1] + red1[2] + red1[3] + ldv1(cls_b, 1, bf);
    int lab = labels[r];
    float m = fmaxf(e0, e1);
    float lse = m + logf(expf(e0 - m) + expf(e1 - m));
    float ce = lse - (lab == 1 ? e1 : e0);
    float w = (lab == 1) ? 5.0f : 1.0f;
    if (maskA[r] == 1){
      atomicAdd(acc, ce * w);
      atomicAdd(acc + 1, 1.0f);
    }
    int pred = (e1 > e0) ? 1 : 0;
    out[1 + r] = (cand[r] == 1 && pred == 1) ? 1.0f : 0.0f;
  }
}

__global__ void finalize1(const float* __restrict__ acc, float* __restrict__ out){
  out[0] = acc[0] / fmaxf(acc[1], 1.0f);
}

extern "C" void kernel_launch(void* const* d_in, const int* in_sizes, int n_in,
                              void* d_out, int out_size, void* d_ws, size_t ws_size,
                              hipStream_t stream)
{
  const void* enc   = d_in[0];
  const void* desc  = d_in[1];
  const int* maskA  = (const int*)d_in[2];
  const int* cand   = (const int*)d_in[3];
  const int* labels = (const int*)d_in[4];
  const void* ipw   = d_in[5];
  const void* ipb   = d_in[6];
  const void* outw  = d_in[7];
  const void* outb  = d_in[8];
  const void* ln1g  = d_in[9];
  const void* ln1b  = d_in[10];
  const void* fw1   = d_in[11];
  const void* fb1   = d_in[12];
  const void* fw2   = d_in[13];
  const void* fb2   = d_in[14];
  const void* ln2g  = d_in[15];
  const void* ln2b  = d_in[16];
  const void* clsw  = d_in[17];
  const void* clsb  = d_in[18];
  float* out = (float*)d_out;

  const int E = 1024, F = 4096, Lc = 9;
  const size_t NE = (size_t)4096 * 1024;            // activation elems
  const size_t NS = (size_t)128 * 512 * 512;        // score elems
  const size_t NF = (size_t)4096 * 4096;            // ffn-mid elems

  float* ws   = (float*)d_ws;
  float* Abuf = ws;                                  // (4096,E) f32
  float* Bf   = Abuf + NE;                           // (4096,E) f32
  float* Qb   = Bf + NE;                             // Q / ctx / ffn-out
  float* Kb   = Qb + NE;                             // K / attn_out
  float* Vb   = Kb + NE;                             // V / A1
  float* Sc   = Vb + NE;                             // scores (128,512,512)
  u16* FFh  = (u16*)(Sc + NS);                       // ffn mid hi (4096,F)
  u16* FFl  = FFh + NF;                              // ffn mid lo
  u16* AspH = FFl + NF;                              // A split
  u16* AspL = AspH + NE;
  u16* BspH = AspL + NE;                             // Bf split (layer-invariant)
  u16* BspL = BspH + NE;
  u16* WipH = BspL + NE;                             // in_proj split (3E,E)
  u16* WipL = WipH + (size_t)3 * E * E;
  u16* WoH  = WipL + (size_t)3 * E * E;              // out_w split (E,E)
  u16* WoL  = WoH + (size_t)E * E;
  u16* W1H  = WoL + (size_t)E * E;                   // ffn_w1 split (F,E)
  u16* W1L  = W1H + (size_t)F * E;
  u16* W2H  = W1L + (size_t)F * E;                   // ffn_w2 split (E,F)
  u16* W2L  = W2H + (size_t)E * F;
  float* acc = (float*)(W2L + (size_t)E * F);        // [sum, count, dtype-flag]
  // overlays in Sc (dead outside qk..attn_ctx window):
  u16* CtxH = (u16*)Sc;
  u16* CtxL = CtxH + NE;
  u16* A1H  = CtxL + NE;
  u16* A1L  = A1H + NE;

  zero2<<<1, 64, 0, stream>>>(acc);
  detect_dtype<<<1, 64, 0, stream>>>((const u16*)enc, acc);
  upcast_flag<<<4096, 256, 0, stream>>>(enc,  (float4*)Abuf, (int)(NE / 4), acc);
  upcast_flag<<<4096, 256, 0, stream>>>(desc, (float4*)Bf,   (int)(NE / 4), acc);
  split8<<<2048, 256, 0, stream>>>(Bf, 0, BspH, BspL, (int)(NE / 8), 0, acc);

  dim3 gP(8, 64, 1);     // BM=64 tiles, N=1024
  dim3 gF1(32, 32, 1);   // BM=128 tiles, N=4096
  for (int l = 0; l < Lc; ++l){
    // weight splits for this layer (flag-aware)
    split8<<<1536, 256, 0, stream>>>(ipw,  (size_t)l * 3 * E * E, WipH, WipL, 3 * E * E / 8, 1, acc);
    split8<<< 512, 256, 0, stream>>>(outw, (size_t)l * E * E,     WoH,  WoL,  E * E / 8,     1, acc);
    split8<<<2048, 256, 0, stream>>>(fw1,  (size_t)l * F * E,     W1H,  W1L,  F * E / 8,     1, acc);
    split8<<<2048, 256, 0, stream>>>(fw2,  (size_t)l * E * F,     W2H,  W2L,  E * F / 8,     1, acc);
    split8<<<2048, 256, 0, stream>>>(Abuf, 0, AspH, AspL, (int)(NE / 8), 0, acc);

    size_t EE = (size_t)E * E;
    gemm_bf3<64><<<gP, 256, 0, stream>>>(AspH, AspL, WipH,          WipL,          ipb, (size_t)l*3*E,       Qb, (u16*)0, (u16*)0, E, E, 0, 0, acc);
    gemm_bf3<64><<<gP, 256, 0, stream>>>(BspH, BspL, WipH + EE,     WipL + EE,     ipb, (size_t)l*3*E + E,   Kb, (u16*)0, (u16*)0, E, E, 0, 0, acc);
    gemm_bf3<64><<<gP, 256, 0, stream>>>(BspH, BspL, WipH + 2*EE,   WipL + 2*EE,   ipb, (size_t)l*3*E + 2*E, Vb, (u16*)0, (u16*)0, E, E, 0, 0, acc);

    gemm_qk<<<dim3(4, 4, 128), 256, 0, stream>>>(Qb, Kb, Sc);
    softmax512<<<65536, 256, 0, stream>>>(Sc);
    attn_ctx<<<dim3(1, 8, 128), 256, 0, stream>>>(Sc, Vb, Qb);     // ctx -> Qb

    split8<<<2048, 256, 0, stream>>>(Qb, 0, CtxH, CtxL, (int)(NE / 8), 0, acc);
    gemm_bf3<64><<<gP, 256, 0, stream>>>(CtxH, CtxL, WoH, WoL, outb, (size_t)l*E, Kb, (u16*)0, (u16*)0, E, E, 0, 0, acc);
    ln_off<<<4096, 256, 0, stream>>>(Abuf, Kb, ln1g, ln1b, (size_t)l*E, Vb, acc);   // A1 -> Vb

    split8<<<2048, 256, 0, stream>>>(Vb, 0, A1H, A1L, (int)(NE / 8), 0, acc);
    gemm_bf3<128><<<gF1, 256, 0, stream>>>(A1H, A1L, W1H, W1L, fb1, (size_t)l*F, (float*)0, FFh, FFl, E, F, 1, 1, acc);
    gemm_bf3<64><<<gP, 256, 0, stream>>>(FFh, FFl, W2H, W2L, fb2, (size_t)l*E, Qb, (u16*)0, (u16*)0, F, E, 0, 0, acc);
    ln_off<<<4096, 256, 0, stream>>>(Vb, Qb, ln2g, ln2b, (size_t)l*E, Abuf, acc);   // A2 -> Abuf
  }

  loss_row<<<4096, 256, 0, stream>>>(Abuf, clsw, clsb, labels, maskA, cand, acc, out, acc);
  finalize1<<<1, 1, 0, stream>>>(acc, out);
}